// Round 2
// baseline (116529.700 us; speedup 1.0000x reference)
//
#include <hip/hip_runtime.h>
#include <math.h>

// Problem dims
#define B_   128
#define S_   400
#define ENC_ 512
#define E_   256
#define H_   512
#define D_   128
#define P_   128
#define V_   30
#define T_   600

// Workspace layout (float units)
#define KEYV_OFF 0
#define VALV_OFF (KEYV_OFF + B_*S_*P_)
#define H1_OFF   (VALV_OFF + B_*S_*P_)
#define C1_OFF   (H1_OFF + 2*B_*H_)
#define H2_OFF   (C1_OFF + B_*H_)
#define C2_OFF   (H2_OFF + 2*B_*D_)
#define CTX_OFF  (C2_OFF + B_*D_)
#define CHR_OFF  (CTX_OFF + B_*P_)
#define WS_FLOATS (CHR_OFF + B_)          // barrier ints live at ws[WS_FLOATS..+3]

#define PRED_N (B_*T_*V_)
#define NBLK 256

__device__ __forceinline__ float sigm_(float x){ return 1.0f/(1.0f + expf(-x)); }

// -------- device-wide sense-reversing barrier (cross-XCD safe: agent atomics + fences) ----
__device__ __forceinline__ void gbar(int* cnt, int* gen){
  __syncthreads();                       // all waves' stores drained (vmcnt0 before s_barrier)
  if (threadIdx.x == 0){
    int g = __hip_atomic_load(gen, __ATOMIC_RELAXED, __HIP_MEMORY_SCOPE_AGENT);
    __threadfence();                     // release: write back this XCD's L2
    int old = __hip_atomic_fetch_add(cnt, 1, __ATOMIC_ACQ_REL, __HIP_MEMORY_SCOPE_AGENT);
    if (old == NBLK-1){
      __hip_atomic_store(cnt, 0, __ATOMIC_RELAXED, __HIP_MEMORY_SCOPE_AGENT);
      __hip_atomic_store(gen, g+1, __ATOMIC_RELEASE, __HIP_MEMORY_SCOPE_AGENT);
    } else {
      while (__hip_atomic_load(gen, __ATOMIC_ACQUIRE, __HIP_MEMORY_SCOPE_AGENT) == g)
        __builtin_amdgcn_s_sleep(2);
    }
    __threadfence();                     // acquire: invalidate L1 so fresh data is re-fetched
  }
  __syncthreads();
}

// ---------------- precompute keyv/valv (unchanged from round 1) -------------------------
__global__ __launch_bounds__(256) void k_kv(const float* __restrict__ enc,
    const float* __restrict__ Wk, const float* __restrict__ bk,
    const float* __restrict__ Wv, const float* __restrict__ bv,
    float* __restrict__ ws)
{
  __shared__ float As[32][68];
  __shared__ float Bs[32][68];
  const int tid = threadIdx.x;
  const int tx = tid & 15, ty = tid >> 4;
  const int n0 = blockIdx.x * 64;
  const int c0 = blockIdx.y * 64;
  float acc[4][4] = {};
  for (int k0 = 0; k0 < ENC_; k0 += 32){
    #pragma unroll
    for (int i = 0; i < 8; ++i){
      int idx = tid + 256*i;
      int kk = idx & 31, nl = idx >> 5;
      As[kk][nl] = enc[(size_t)(n0+nl)*ENC_ + k0 + kk];
    }
    #pragma unroll
    for (int i = 0; i < 8; ++i){
      int idx = tid + 256*i;
      int kk = idx & 31, cl = idx >> 5;
      int c = c0 + cl; int p = c & 127;
      const float* W = (c < 128) ? Wk : Wv;
      Bs[kk][cl] = W[(size_t)p*ENC_ + k0 + kk];
    }
    __syncthreads();
    #pragma unroll
    for (int kk = 0; kk < 32; ++kk){
      float4 a4 = *(const float4*)&As[kk][ty*4];
      float4 b4 = *(const float4*)&Bs[kk][tx*4];
      float aa[4] = {a4.x, a4.y, a4.z, a4.w};
      float bb[4] = {b4.x, b4.y, b4.z, b4.w};
      #pragma unroll
      for (int i=0;i<4;++i)
        #pragma unroll
        for (int j=0;j<4;++j) acc[i][j] += aa[i]*bb[j];
    }
    __syncthreads();
  }
  float* keyv = ws + KEYV_OFF;
  float* valv = ws + VALV_OFF;
  #pragma unroll
  for (int i=0;i<4;++i){
    int n = n0 + ty*4 + i; int b = n / S_; int s = n - b*S_;
    #pragma unroll
    for (int j=0;j<4;++j){
      int c = c0 + tx*4 + j;
      float v = acc[i][j];
      if (c < 128) keyv[((size_t)b*S_+s)*P_ + c]       = v + bk[c];
      else         valv[((size_t)b*S_+s)*P_ + (c-128)] = v + bv[c-128];
    }
  }
}

// ---------------- persistent kernel: full T-loop, 3 grid barriers per step --------------
__global__ __launch_bounds__(256, 1) void k_persist(
    const float* __restrict__ embed,
    const float* __restrict__ Wih1, const float* __restrict__ Whh1,
    const float* __restrict__ bih1, const float* __restrict__ bhh1,
    const float* __restrict__ Wih2, const float* __restrict__ Whh2,
    const float* __restrict__ bih2, const float* __restrict__ bhh2,
    const float* __restrict__ Wq, const float* __restrict__ bq,
    const float* __restrict__ bchar, const int* __restrict__ lens,
    float* ws, float* out)
{
  extern __shared__ float smem[];
  const int tid = threadIdx.x;
  const int bid = blockIdx.x;
  int* cnt = (int*)(ws + WS_FLOATS);
  int* gen = cnt + 1;

  float* c1g  = ws + C1_OFF;
  float* c2g  = ws + C2_OFF;
  float* ctxg = ws + CTX_OFF;
  int*   chrg = (int*)(ws + CHR_OFF);

  for (int t = 0; t < T_; ++t){
    // ================= Phase 1: LSTM1 (all 256 blocks) ===================
    {
      const int ib = bid >> 6, ug = bid & 63;
      const int b0 = ib * 32;
      float* Xs  = smem;               // [64][36]
      float* Wt  = smem + 2304;        // [64][36]
      float* red = smem + 4608;        // [4096]
      const float* h1old = ws + H1_OFF + (size_t)(t&1)*B_*H_;
      float*       h1new = ws + H1_OFF + (size_t)((t+1)&1)*B_*H_;

      const int sil = tid & 31, skb = tid >> 5;
      const int sb  = b0 + sil;
      const int sch = chrg[sb];
      const int wrow = tid & 31, wkb = tid >> 5;
      const int gg = wrow >> 3, uu = wrow & 7;
      const int R  = gg*H_ + ug*8 + uu;
      const int w  = tid >> 6, lane = tid & 63;
      const int ii = lane >> 3, rg = lane & 7;

      float acc[4][4] = {};
      float xr[8], wr[8];
      {
        int kx = skb*8;
        const float* xs = (kx < 256) ? embed + (size_t)sch*E_ + kx
                        : (kx < 384) ? ctxg + sb*P_ + (kx-256)
                                     : h1old + sb*H_ + (kx-384);
        float4 a = *(const float4*)xs, b = *(const float4*)(xs+4);
        xr[0]=a.x; xr[1]=a.y; xr[2]=a.z; xr[3]=a.w; xr[4]=b.x; xr[5]=b.y; xr[6]=b.z; xr[7]=b.w;
        int kw = wkb*8;
        const float* wsrc = (kw < 384) ? Wih1 + (size_t)R*384 + kw
                                       : Whh1 + (size_t)R*H_ + (kw-384);
        float4 c = *(const float4*)wsrc, d = *(const float4*)(wsrc+4);
        wr[0]=c.x; wr[1]=c.y; wr[2]=c.z; wr[3]=c.w; wr[4]=d.x; wr[5]=d.y; wr[6]=d.z; wr[7]=d.w;
      }
      for (int p = 0; p < 14; ++p){
        #pragma unroll
        for (int q = 0; q < 8; ++q) Xs[(skb*8+q)*36 + sil] = xr[q];
        #pragma unroll
        for (int q = 0; q < 8; ++q) Wt[(wkb*8+q)*36 + wrow] = wr[q];
        __syncthreads();
        if (p < 13){
          int kx = (p+1)*64 + skb*8;
          const float* xs = (kx < 256) ? embed + (size_t)sch*E_ + kx
                          : (kx < 384) ? ctxg + sb*P_ + (kx-256)
                                       : h1old + sb*H_ + (kx-384);
          float4 a = *(const float4*)xs, b = *(const float4*)(xs+4);
          xr[0]=a.x; xr[1]=a.y; xr[2]=a.z; xr[3]=a.w; xr[4]=b.x; xr[5]=b.y; xr[6]=b.z; xr[7]=b.w;
          int kw = (p+1)*64 + wkb*8;
          const float* wsrc = (kw < 384) ? Wih1 + (size_t)R*384 + kw
                                         : Whh1 + (size_t)R*H_ + (kw-384);
          float4 c = *(const float4*)wsrc, d = *(const float4*)(wsrc+4);
          wr[0]=c.x; wr[1]=c.y; wr[2]=c.z; wr[3]=c.w; wr[4]=d.x; wr[5]=d.y; wr[6]=d.z; wr[7]=d.w;
        }
        #pragma unroll
        for (int kq = 0; kq < 16; ++kq){
          int kk = w*16 + kq;
          float4 xv = *(const float4*)&Xs[kk*36 + ii*4];
          float4 wv = *(const float4*)&Wt[kk*36 + rg*4];
          float xa[4] = {xv.x, xv.y, xv.z, xv.w};
          float wa[4] = {wv.x, wv.y, wv.z, wv.w};
          #pragma unroll
          for (int a=0;a<4;++a)
            #pragma unroll
            for (int r=0;r<4;++r) acc[a][r] += xa[a]*wa[r];
        }
        __syncthreads();
      }
      float* rb = red + w*1024;
      #pragma unroll
      for (int a=0;a<4;++a)
        *(float4*)&rb[(ii*4+a)*32 + rg*4] = make_float4(acc[a][0],acc[a][1],acc[a][2],acc[a][3]);
      __syncthreads();
      {
        const int il = tid >> 3, uo = tid & 7;
        const int J = ug*8 + uo;
        const int b = b0 + il;
        float gate[4];
        #pragma unroll
        for (int g4=0; g4<4; ++g4){
          int o = il*32 + g4*8 + uo;
          gate[g4] = red[o] + red[1024+o] + red[2048+o] + red[3072+o]
                   + bih1[g4*H_ + J] + bhh1[g4*H_ + J];
        }
        float cold = c1g[b*H_ + J];
        float cn = sigm_(gate[1])*cold + sigm_(gate[0])*tanhf(gate[2]);
        float hn = sigm_(gate[3])*tanhf(cn);
        c1g[b*H_ + J]   = cn;
        h1new[b*H_ + J] = hn;
      }
    }
    gbar(cnt, gen);

    // ================= Phase 2: LSTM2 (blocks 0..127) ====================
    if (bid < 128){
      const int ib = bid >> 6, ug = bid & 63;
      const int b0 = ib * 64;
      float* Xs  = smem;               // [64][68]
      float* Wt  = smem + 4352;        // [64][12]
      float* red = smem + 5120;        // [2048]
      const float* h1new = ws + H1_OFF + (size_t)((t+1)&1)*B_*H_;
      const float* h2old = ws + H2_OFF + (size_t)(t&1)*B_*D_;
      float*       h2new = ws + H2_OFF + (size_t)((t+1)&1)*B_*D_;

      const int il = tid & 63, kb = tid >> 6;
      const int bx = b0 + il;
      const int r2 = tid & 7, kb2 = tid >> 3;     // W staging (tid<64)
      const int R2 = (r2>>1)*D_ + ug*2 + (r2&1);
      const int w  = tid >> 6, lane = tid & 63;
      const int ig2 = lane >> 2, rg2 = lane & 3;

      float acc[4][2] = {};
      float xr2[16], wr2[8];
      {
        int kx = kb*16;
        const float* xs = (kx < 512) ? h1new + bx*H_ + kx : h2old + bx*D_ + (kx-512);
        #pragma unroll
        for (int j=0;j<4;++j){
          float4 v = *(const float4*)(xs + j*4);
          xr2[j*4]=v.x; xr2[j*4+1]=v.y; xr2[j*4+2]=v.z; xr2[j*4+3]=v.w;
        }
        if (tid < 64){
          int kw = kb2*8;
          const float* wsrc = (kw < 512) ? Wih2 + (size_t)R2*H_ + kw
                                         : Whh2 + (size_t)R2*D_ + (kw-512);
          float4 c = *(const float4*)wsrc, d = *(const float4*)(wsrc+4);
          wr2[0]=c.x; wr2[1]=c.y; wr2[2]=c.z; wr2[3]=c.w; wr2[4]=d.x; wr2[5]=d.y; wr2[6]=d.z; wr2[7]=d.w;
        }
      }
      for (int p = 0; p < 10; ++p){
        #pragma unroll
        for (int j=0;j<16;++j) Xs[(kb*16+j)*68 + il] = xr2[j];
        if (tid < 64){
          #pragma unroll
          for (int q=0;q<8;++q) Wt[(kb2*8+q)*12 + r2] = wr2[q];
        }
        __syncthreads();
        if (p < 9){
          int kx = (p+1)*64 + kb*16;
          const float* xs = (kx < 512) ? h1new + bx*H_ + kx : h2old + bx*D_ + (kx-512);
          #pragma unroll
          for (int j=0;j<4;++j){
            float4 v = *(const float4*)(xs + j*4);
            xr2[j*4]=v.x; xr2[j*4+1]=v.y; xr2[j*4+2]=v.z; xr2[j*4+3]=v.w;
          }
          if (tid < 64){
            int kw = (p+1)*64 + kb2*8;
            const float* wsrc = (kw < 512) ? Wih2 + (size_t)R2*H_ + kw
                                           : Whh2 + (size_t)R2*D_ + (kw-512);
            float4 c = *(const float4*)wsrc, d = *(const float4*)(wsrc+4);
            wr2[0]=c.x; wr2[1]=c.y; wr2[2]=c.z; wr2[3]=c.w; wr2[4]=d.x; wr2[5]=d.y; wr2[6]=d.z; wr2[7]=d.w;
          }
        }
        #pragma unroll
        for (int kq = 0; kq < 16; ++kq){
          int kk = w*16 + kq;
          float4 xv = *(const float4*)&Xs[kk*68 + ig2*4];
          float2 wv = *(const float2*)&Wt[kk*12 + rg2*2];
          acc[0][0] += xv.x*wv.x; acc[0][1] += xv.x*wv.y;
          acc[1][0] += xv.y*wv.x; acc[1][1] += xv.y*wv.y;
          acc[2][0] += xv.z*wv.x; acc[2][1] += xv.z*wv.y;
          acc[3][0] += xv.w*wv.x; acc[3][1] += xv.w*wv.y;
        }
        __syncthreads();
      }
      #pragma unroll
      for (int a=0;a<4;++a){
        red[w*512 + (ig2*4+a)*8 + rg2*2 + 0] = acc[a][0];
        red[w*512 + (ig2*4+a)*8 + rg2*2 + 1] = acc[a][1];
      }
      __syncthreads();
      if (tid < 128){
        const int il2 = tid >> 1, uo = tid & 1;
        const int J = ug*2 + uo;
        const int b = b0 + il2;
        float gate[4];
        #pragma unroll
        for (int g4=0; g4<4; ++g4){
          int o = il2*8 + g4*2 + uo;
          gate[g4] = red[o] + red[512+o] + red[1024+o] + red[1536+o]
                   + bih2[g4*D_ + J] + bhh2[g4*D_ + J];
        }
        float cold = c2g[b*D_ + J];
        float cn = sigm_(gate[1])*cold + sigm_(gate[0])*tanhf(gate[2]);
        float hn = sigm_(gate[3])*tanhf(cn);
        c2g[b*D_ + J]   = cn;
        h2new[b*D_ + J] = hn;
      }
    }
    gbar(cnt, gen);

    // ================= Phase 3: attention + pred + argmax (blocks 0..127) =
    if (bid < 128){
      const int b = bid;
      float* hs    = smem;         // 128
      float* qs    = smem + 128;   // 128
      float* es    = smem + 256;   // 400
      float* red3  = smem + 656;   // 256
      float* oes   = smem + 912;   // 256
      float* preds = smem + 1168;  // 32
      const float* h2new = ws + H2_OFF + (size_t)((t+1)&1)*B_*D_;
      const float* keyv = ws + KEYV_OFF + (size_t)b*S_*P_;
      const float* valv = ws + VALV_OFF + (size_t)b*S_*P_;

      if (tid < 128) hs[tid] = h2new[b*D_ + tid];
      __syncthreads();
      if (tid < 128){
        float a = bq[tid];
        const float4* row = (const float4*)(Wq + (size_t)tid*D_);
        #pragma unroll 8
        for (int d=0; d<32; ++d){
          float4 wv = row[d];
          a += wv.x*hs[d*4] + wv.y*hs[d*4+1] + wv.z*hs[d*4+2] + wv.w*hs[d*4+3];
        }
        qs[tid] = a;
      }
      __syncthreads();
      const int len = lens[b];
      for (int s = tid; s < S_; s += 256){
        const float4* kr = (const float4*)(keyv + (size_t)s*P_);
        float a = 0.f;
        #pragma unroll 8
        for (int d=0; d<32; ++d){
          float4 kv = kr[d];
          a += kv.x*qs[d*4] + kv.y*qs[d*4+1] + kv.z*qs[d*4+2] + kv.w*qs[d*4+3];
        }
        es[s] = (s < len) ? a * 0.08838834764831845f : -1e9f;
      }
      __syncthreads();
      float m = -INFINITY;
      for (int s = tid; s < S_; s += 256) m = fmaxf(m, es[s]);
      red3[tid] = m; __syncthreads();
      for (int o = 128; o > 0; o >>= 1){ if (tid < o) red3[tid] = fmaxf(red3[tid], red3[tid+o]); __syncthreads(); }
      m = red3[0]; __syncthreads();
      float psum = 0.f;
      for (int s = tid; s < S_; s += 256){ float p = expf(es[s]-m); es[s] = p; psum += p; }
      red3[tid] = psum; __syncthreads();
      for (int o = 128; o > 0; o >>= 1){ if (tid < o) red3[tid] += red3[tid+o]; __syncthreads(); }
      const float sum = red3[0]; __syncthreads();
      {
        const int p = tid & 127, half = tid >> 7;
        float a = 0.f;
        const float* vp = valv + p;
        #pragma unroll 4
        for (int s = half*200; s < half*200+200; ++s) a += es[s] * vp[(size_t)s*P_];
        red3[tid] = a;
      }
      __syncthreads();
      if (tid < 128){
        float c = (red3[tid] + red3[tid+128]) / sum;
        ctxg[b*P_ + tid] = c;
        oes[tid] = qs[tid]; oes[128+tid] = c;
      }
      __syncthreads();
      {
        const int v = tid >> 3, k8 = tid & 7;
        float a = 0.f;
        if (v < V_){
          const float* er = embed + (size_t)v*E_ + k8*32;
          const float* oe = oes + k8*32;
          #pragma unroll
          for (int k=0;k<32;++k) a += er[k]*oe[k];
        }
        a += __shfl_down(a, 4, 8);
        a += __shfl_down(a, 2, 8);
        a += __shfl_down(a, 1, 8);
        if (v < V_ && k8 == 0){
          float pv = a + bchar[v];
          preds[v] = pv;
          out[((size_t)b*T_ + t)*V_ + v] = pv;
        }
      }
      __syncthreads();
      if (tid < 32){
        float val = (tid < V_) ? preds[tid] : -INFINITY;
        int idx = tid;
        #pragma unroll
        for (int o = 16; o > 0; o >>= 1){
          float ov = __shfl_down(val, o, 32);
          int oi = __shfl_down(idx, o, 32);
          if (ov > val || (ov == val && oi < idx)){ val = ov; idx = oi; }
        }
        if (tid == 0) chrg[b] = idx;
      }
      if (b == 0){
        for (int s = tid; s < S_; s += 256) out[PRED_N + (size_t)t*S_ + s] = es[s]/sum;
      }
    }
    gbar(cnt, gen);
  }
}

extern "C" void kernel_launch(void* const* d_in, const int* in_sizes, int n_in,
                              void* d_out, int out_size, void* d_ws, size_t ws_size,
                              hipStream_t stream)
{
  (void)in_sizes; (void)n_in; (void)out_size; (void)ws_size;
  const float* enc   = (const float*)d_in[0];
  const int*   lens  = (const int*)d_in[1];
  const float* embed = (const float*)d_in[2];
  const float* Wih1  = (const float*)d_in[3];
  const float* Whh1  = (const float*)d_in[4];
  const float* bih1  = (const float*)d_in[5];
  const float* bhh1  = (const float*)d_in[6];
  const float* Wih2  = (const float*)d_in[7];
  const float* Whh2  = (const float*)d_in[8];
  const float* bih2  = (const float*)d_in[9];
  const float* bhh2  = (const float*)d_in[10];
  const float* Wk    = (const float*)d_in[11];
  const float* bk    = (const float*)d_in[12];
  const float* Wv    = (const float*)d_in[13];
  const float* bv    = (const float*)d_in[14];
  const float* Wq    = (const float*)d_in[15];
  const float* bq    = (const float*)d_in[16];
  const float* bchar = (const float*)d_in[17];
  float* out = (float*)d_out;
  float* ws  = (float*)d_ws;

  // zero recurrent state + barrier words (poison-proof, replay-deterministic)
  hipMemsetAsync((char*)d_ws + (size_t)H1_OFF*sizeof(float), 0,
                 (size_t)(WS_FLOATS - H1_OFF + 4)*sizeof(float), stream);
  hipLaunchKernelGGL(k_kv, dim3(800,4), dim3(256), 0, stream, enc, Wk, bk, Wv, bv, ws);

  // 84 KB dynamic LDS forces 1 block/CU -> 256 blocks all co-resident (grid barrier safe)
  hipFuncSetAttribute((const void*)k_persist,
                      hipFuncAttributeMaxDynamicSharedMemorySize, 86016);
  hipLaunchKernelGGL(k_persist, dim3(NBLK), dim3(256), 86016, stream,
                     embed, Wih1, Whh1, bih1, bhh1,
                     Wih2, Whh2, bih2, bhh2,
                     Wq, bq, bchar, lens, ws, out);
}

// Round 3
// 49804.150 us; speedup vs baseline: 2.3398x; 2.3398x over previous
//
#include <hip/hip_runtime.h>
#include <math.h>

// Problem dims
#define B_   128
#define S_   400
#define ENC_ 512
#define E_   256
#define H_   512
#define D_   128
#define P_   128
#define V_   30
#define T_   600

// Workspace layout (float units)
#define KEYV_OFF 0
#define VALV_OFF (KEYV_OFF + B_*S_*P_)
#define H1_OFF   (VALV_OFF + B_*S_*P_)
#define C1_OFF   (H1_OFF + 2*B_*H_)
#define H2_OFF   (C1_OFF + B_*H_)
#define C2_OFF   (H2_OFF + 2*B_*D_)
#define CTX_OFF  (C2_OFF + B_*D_)
#define CHR_OFF  (CTX_OFF + B_*P_)
#define WS_FLOATS (CHR_OFF + B_)          // barrier ints live at ws[WS_FLOATS..]

#define PRED_N (B_*T_*V_)
#define NBLK 256

__device__ __forceinline__ float sigm_(float x){ return 1.0f/(1.0f + expf(-x)); }

// --- agent-scope relaxed atomics: sc1 loads/stores that bypass L1/L2 (coherence point) ---
__device__ __forceinline__ float ldA(const float* p){
  return __hip_atomic_load(p, __ATOMIC_RELAXED, __HIP_MEMORY_SCOPE_AGENT);
}
__device__ __forceinline__ void stA(float* p, float v){
  __hip_atomic_store(p, v, __ATOMIC_RELAXED, __HIP_MEMORY_SCOPE_AGENT);
}
__device__ __forceinline__ int ldAi(const int* p){
  return __hip_atomic_load(p, __ATOMIC_RELAXED, __HIP_MEMORY_SCOPE_AGENT);
}
__device__ __forceinline__ void stAi(int* p, int v){
  __hip_atomic_store(p, v, __ATOMIC_RELAXED, __HIP_MEMORY_SCOPE_AGENT);
}

// ---- fence-free grid barrier: tree counters, relaxed atomics only, NO L2 flushes -------
// bar[0]=gen, bar[32]=root cnt, bar[64+g*32]=leaf cnt g (g = bid&7), lines 128B apart.
__device__ __forceinline__ void gbar(int* bar){
  __syncthreads();   // drains each wave's vmcnt -> all sc1 state stores at coherence point
  if (threadIdx.x == 0){
    const int g0 = __hip_atomic_load(bar, __ATOMIC_RELAXED, __HIP_MEMORY_SCOPE_AGENT);
    asm volatile("" ::: "memory");
    int* leaf = bar + 64 + (blockIdx.x & 7)*32;
    int lo = __hip_atomic_fetch_add(leaf, 1, __ATOMIC_RELAXED, __HIP_MEMORY_SCOPE_AGENT);
    bool done = false;
    if (lo == 31){
      int ro = __hip_atomic_fetch_add(bar+32, 1, __ATOMIC_RELAXED, __HIP_MEMORY_SCOPE_AGENT);
      if (ro == 7){
        #pragma unroll
        for (int i=0;i<8;++i)
          __hip_atomic_store(bar+64+i*32, 0, __ATOMIC_RELAXED, __HIP_MEMORY_SCOPE_AGENT);
        __hip_atomic_store(bar+32, 0, __ATOMIC_RELAXED, __HIP_MEMORY_SCOPE_AGENT);
        asm volatile("s_waitcnt vmcnt(0)" ::: "memory");  // resets committed before gen bump
        __hip_atomic_fetch_add(bar, 1, __ATOMIC_RELAXED, __HIP_MEMORY_SCOPE_AGENT);
        done = true;
      }
    }
    if (!done){
      while (__hip_atomic_load(bar, __ATOMIC_RELAXED, __HIP_MEMORY_SCOPE_AGENT) == g0)
        __builtin_amdgcn_s_sleep(4);
    }
  }
  __syncthreads();
}

// ---------------- precompute keyv/valv (unchanged) --------------------------------------
__global__ __launch_bounds__(256) void k_kv(const float* __restrict__ enc,
    const float* __restrict__ Wk, const float* __restrict__ bk,
    const float* __restrict__ Wv, const float* __restrict__ bv,
    float* __restrict__ ws)
{
  __shared__ float As[32][68];
  __shared__ float Bs[32][68];
  const int tid = threadIdx.x;
  const int tx = tid & 15, ty = tid >> 4;
  const int n0 = blockIdx.x * 64;
  const int c0 = blockIdx.y * 64;
  float acc[4][4] = {};
  for (int k0 = 0; k0 < ENC_; k0 += 32){
    #pragma unroll
    for (int i = 0; i < 8; ++i){
      int idx = tid + 256*i;
      int kk = idx & 31, nl = idx >> 5;
      As[kk][nl] = enc[(size_t)(n0+nl)*ENC_ + k0 + kk];
    }
    #pragma unroll
    for (int i = 0; i < 8; ++i){
      int idx = tid + 256*i;
      int kk = idx & 31, cl = idx >> 5;
      int c = c0 + cl; int p = c & 127;
      const float* W = (c < 128) ? Wk : Wv;
      Bs[kk][cl] = W[(size_t)p*ENC_ + k0 + kk];
    }
    __syncthreads();
    #pragma unroll
    for (int kk = 0; kk < 32; ++kk){
      float4 a4 = *(const float4*)&As[kk][ty*4];
      float4 b4 = *(const float4*)&Bs[kk][tx*4];
      float aa[4] = {a4.x, a4.y, a4.z, a4.w};
      float bb[4] = {b4.x, b4.y, b4.z, b4.w};
      #pragma unroll
      for (int i=0;i<4;++i)
        #pragma unroll
        for (int j=0;j<4;++j) acc[i][j] += aa[i]*bb[j];
    }
    __syncthreads();
  }
  float* keyv = ws + KEYV_OFF;
  float* valv = ws + VALV_OFF;
  #pragma unroll
  for (int i=0;i<4;++i){
    int n = n0 + ty*4 + i; int b = n / S_; int s = n - b*S_;
    #pragma unroll
    for (int j=0;j<4;++j){
      int c = c0 + tx*4 + j;
      float v = acc[i][j];
      if (c < 128) keyv[((size_t)b*S_+s)*P_ + c]       = v + bk[c];
      else         valv[((size_t)b*S_+s)*P_ + (c-128)] = v + bv[c-128];
    }
  }
}

// ---------------- persistent kernel: full T-loop, 3 fence-free barriers per step --------
__global__ __launch_bounds__(256, 1) void k_persist(
    const float* __restrict__ embed,
    const float* __restrict__ Wih1, const float* __restrict__ Whh1,
    const float* __restrict__ bih1, const float* __restrict__ bhh1,
    const float* __restrict__ Wih2, const float* __restrict__ Whh2,
    const float* __restrict__ bih2, const float* __restrict__ bhh2,
    const float* __restrict__ Wq, const float* __restrict__ bq,
    const float* __restrict__ bchar, const int* __restrict__ lens,
    float* ws, float* out)
{
  extern __shared__ float smem[];
  const int tid = threadIdx.x;
  const int bid = blockIdx.x;
  int* bar = (int*)(ws + WS_FLOATS);

  float* c1g  = ws + C1_OFF;   // block-private across steps -> normal cached access
  float* c2g  = ws + C2_OFF;   // block-private across steps -> normal cached access
  float* ctxg = ws + CTX_OFF;  // cross-block -> sc1
  int*   chrg = (int*)(ws + CHR_OFF); // cross-block -> sc1

  for (int t = 0; t < T_; ++t){
    // ================= Phase 1: LSTM1 (all 256 blocks) ===================
    {
      const int ib = bid >> 6, ug = bid & 63;
      const int b0 = ib * 32;
      float* Xs  = smem;               // [64][36]
      float* Wt  = smem + 2304;        // [64][36]
      float* red = smem + 4608;        // [4096]
      const float* h1old = ws + H1_OFF + (size_t)(t&1)*B_*H_;
      float*       h1new = ws + H1_OFF + (size_t)((t+1)&1)*B_*H_;

      const int sil = tid & 31, skb = tid >> 5;
      const int sb  = b0 + sil;
      const int sch = ldAi(&chrg[sb]);
      const int wrow = tid & 31, wkb = tid >> 5;
      const int gg = wrow >> 3, uu = wrow & 7;
      const int R  = gg*H_ + ug*8 + uu;
      const int w  = tid >> 6, lane = tid & 63;
      const int ii = lane >> 3, rg = lane & 7;

      float acc[4][4] = {};
      float xr[8], wr[8];
      {
        int kx = skb*8;
        if (kx < 256){
          const float* xs = embed + (size_t)sch*E_ + kx;
          float4 a = *(const float4*)xs, b = *(const float4*)(xs+4);
          xr[0]=a.x; xr[1]=a.y; xr[2]=a.z; xr[3]=a.w; xr[4]=b.x; xr[5]=b.y; xr[6]=b.z; xr[7]=b.w;
        } else if (kx < 384){
          const float* xs = ctxg + sb*P_ + (kx-256);
          #pragma unroll
          for (int j=0;j<8;++j) xr[j] = ldA(xs+j);
        } else {
          const float* xs = h1old + sb*H_ + (kx-384);
          #pragma unroll
          for (int j=0;j<8;++j) xr[j] = ldA(xs+j);
        }
        int kw = wkb*8;
        const float* wsrc = (kw < 384) ? Wih1 + (size_t)R*384 + kw
                                       : Whh1 + (size_t)R*H_ + (kw-384);
        float4 c = *(const float4*)wsrc, d = *(const float4*)(wsrc+4);
        wr[0]=c.x; wr[1]=c.y; wr[2]=c.z; wr[3]=c.w; wr[4]=d.x; wr[5]=d.y; wr[6]=d.z; wr[7]=d.w;
      }
      for (int p = 0; p < 14; ++p){
        #pragma unroll
        for (int q = 0; q < 8; ++q) Xs[(skb*8+q)*36 + sil] = xr[q];
        #pragma unroll
        for (int q = 0; q < 8; ++q) Wt[(wkb*8+q)*36 + wrow] = wr[q];
        __syncthreads();
        if (p < 13){
          int kx = (p+1)*64 + skb*8;
          if (kx < 256){
            const float* xs = embed + (size_t)sch*E_ + kx;
            float4 a = *(const float4*)xs, b = *(const float4*)(xs+4);
            xr[0]=a.x; xr[1]=a.y; xr[2]=a.z; xr[3]=a.w; xr[4]=b.x; xr[5]=b.y; xr[6]=b.z; xr[7]=b.w;
          } else if (kx < 384){
            const float* xs = ctxg + sb*P_ + (kx-256);
            #pragma unroll
            for (int j=0;j<8;++j) xr[j] = ldA(xs+j);
          } else {
            const float* xs = h1old + sb*H_ + (kx-384);
            #pragma unroll
            for (int j=0;j<8;++j) xr[j] = ldA(xs+j);
          }
          int kw = (p+1)*64 + wkb*8;
          const float* wsrc = (kw < 384) ? Wih1 + (size_t)R*384 + kw
                                         : Whh1 + (size_t)R*H_ + (kw-384);
          float4 c = *(const float4*)wsrc, d = *(const float4*)(wsrc+4);
          wr[0]=c.x; wr[1]=c.y; wr[2]=c.z; wr[3]=c.w; wr[4]=d.x; wr[5]=d.y; wr[6]=d.z; wr[7]=d.w;
        }
        #pragma unroll
        for (int kq = 0; kq < 16; ++kq){
          int kk = w*16 + kq;
          float4 xv = *(const float4*)&Xs[kk*36 + ii*4];
          float4 wv = *(const float4*)&Wt[kk*36 + rg*4];
          float xa[4] = {xv.x, xv.y, xv.z, xv.w};
          float wa[4] = {wv.x, wv.y, wv.z, wv.w};
          #pragma unroll
          for (int a=0;a<4;++a)
            #pragma unroll
            for (int r=0;r<4;++r) acc[a][r] += xa[a]*wa[r];
        }
        __syncthreads();
      }
      float* rb = red + w*1024;
      #pragma unroll
      for (int a=0;a<4;++a)
        *(float4*)&rb[(ii*4+a)*32 + rg*4] = make_float4(acc[a][0],acc[a][1],acc[a][2],acc[a][3]);
      __syncthreads();
      {
        const int il = tid >> 3, uo = tid & 7;
        const int J = ug*8 + uo;
        const int b = b0 + il;
        float gate[4];
        #pragma unroll
        for (int g4=0; g4<4; ++g4){
          int o = il*32 + g4*8 + uo;
          gate[g4] = red[o] + red[1024+o] + red[2048+o] + red[3072+o]
                   + bih1[g4*H_ + J] + bhh1[g4*H_ + J];
        }
        float cold = c1g[b*H_ + J];
        float cn = sigm_(gate[1])*cold + sigm_(gate[0])*tanhf(gate[2]);
        float hn = sigm_(gate[3])*tanhf(cn);
        c1g[b*H_ + J] = cn;                 // private: normal store
        stA(&h1new[b*H_ + J], hn);          // cross-block: sc1
      }
    }
    gbar(bar);

    // ================= Phase 2: LSTM2 (blocks 0..127) ====================
    if (bid < 128){
      const int ib = bid >> 6, ug = bid & 63;
      const int b0 = ib * 64;
      float* Xs  = smem;               // [64][68]
      float* Wt  = smem + 4352;        // [64][12]
      float* red = smem + 5120;        // [2048]
      const float* h1new = ws + H1_OFF + (size_t)((t+1)&1)*B_*H_;
      const float* h2old = ws + H2_OFF + (size_t)(t&1)*B_*D_;
      float*       h2new = ws + H2_OFF + (size_t)((t+1)&1)*B_*D_;

      const int il = tid & 63, kb = tid >> 6;
      const int bx = b0 + il;
      const int r2 = tid & 7, kb2 = tid >> 3;
      const int R2 = (r2>>1)*D_ + ug*2 + (r2&1);
      const int w  = tid >> 6, lane = tid & 63;
      const int ig2 = lane >> 2, rg2 = lane & 3;

      float acc[4][2] = {};
      float xr2[16], wr2[8];
      {
        int kx = kb*16;
        const float* xs = (kx < 512) ? h1new + bx*H_ + kx : h2old + bx*D_ + (kx-512);
        #pragma unroll
        for (int j=0;j<16;++j) xr2[j] = ldA(xs+j);
        if (tid < 64){
          int kw = kb2*8;
          const float* wsrc = (kw < 512) ? Wih2 + (size_t)R2*H_ + kw
                                         : Whh2 + (size_t)R2*D_ + (kw-512);
          float4 c = *(const float4*)wsrc, d = *(const float4*)(wsrc+4);
          wr2[0]=c.x; wr2[1]=c.y; wr2[2]=c.z; wr2[3]=c.w; wr2[4]=d.x; wr2[5]=d.y; wr2[6]=d.z; wr2[7]=d.w;
        }
      }
      for (int p = 0; p < 10; ++p){
        #pragma unroll
        for (int j=0;j<16;++j) Xs[(kb*16+j)*68 + il] = xr2[j];
        if (tid < 64){
          #pragma unroll
          for (int q=0;q<8;++q) Wt[(kb2*8+q)*12 + r2] = wr2[q];
        }
        __syncthreads();
        if (p < 9){
          int kx = (p+1)*64 + kb*16;
          const float* xs = (kx < 512) ? h1new + bx*H_ + kx : h2old + bx*D_ + (kx-512);
          #pragma unroll
          for (int j=0;j<16;++j) xr2[j] = ldA(xs+j);
          if (tid < 64){
            int kw = (p+1)*64 + kb2*8;
            const float* wsrc = (kw < 512) ? Wih2 + (size_t)R2*H_ + kw
                                           : Whh2 + (size_t)R2*D_ + (kw-512);
            float4 c = *(const float4*)wsrc, d = *(const float4*)(wsrc+4);
            wr2[0]=c.x; wr2[1]=c.y; wr2[2]=c.z; wr2[3]=c.w; wr2[4]=d.x; wr2[5]=d.y; wr2[6]=d.z; wr2[7]=d.w;
          }
        }
        #pragma unroll
        for (int kq = 0; kq < 16; ++kq){
          int kk = w*16 + kq;
          float4 xv = *(const float4*)&Xs[kk*68 + ig2*4];
          float2 wv = *(const float2*)&Wt[kk*12 + rg2*2];
          acc[0][0] += xv.x*wv.x; acc[0][1] += xv.x*wv.y;
          acc[1][0] += xv.y*wv.x; acc[1][1] += xv.y*wv.y;
          acc[2][0] += xv.z*wv.x; acc[2][1] += xv.z*wv.y;
          acc[3][0] += xv.w*wv.x; acc[3][1] += xv.w*wv.y;
        }
        __syncthreads();
      }
      #pragma unroll
      for (int a=0;a<4;++a){
        red[w*512 + (ig2*4+a)*8 + rg2*2 + 0] = acc[a][0];
        red[w*512 + (ig2*4+a)*8 + rg2*2 + 1] = acc[a][1];
      }
      __syncthreads();
      if (tid < 128){
        const int il2 = tid >> 1, uo = tid & 1;
        const int J = ug*2 + uo;
        const int b = b0 + il2;
        float gate[4];
        #pragma unroll
        for (int g4=0; g4<4; ++g4){
          int o = il2*8 + g4*2 + uo;
          gate[g4] = red[o] + red[512+o] + red[1024+o] + red[1536+o]
                   + bih2[g4*D_ + J] + bhh2[g4*D_ + J];
        }
        float cold = c2g[b*D_ + J];
        float cn = sigm_(gate[1])*cold + sigm_(gate[0])*tanhf(gate[2]);
        float hn = sigm_(gate[3])*tanhf(cn);
        c2g[b*D_ + J] = cn;                 // private: normal store
        stA(&h2new[b*D_ + J], hn);          // cross-block: sc1
      }
    }
    gbar(bar);

    // ================= Phase 3: attention + pred + argmax (blocks 0..127) =
    if (bid < 128){
      const int b = bid;
      float* hs    = smem;         // 128
      float* qs    = smem + 128;   // 128
      float* es    = smem + 256;   // 400
      float* red3  = smem + 656;   // 256
      float* oes   = smem + 912;   // 256
      float* preds = smem + 1168;  // 32
      const float* h2new = ws + H2_OFF + (size_t)((t+1)&1)*B_*D_;
      const float* keyv = ws + KEYV_OFF + (size_t)b*S_*P_;
      const float* valv = ws + VALV_OFF + (size_t)b*S_*P_;

      if (tid < 128) hs[tid] = ldA(&h2new[b*D_ + tid]);
      __syncthreads();
      if (tid < 128){
        float a = bq[tid];
        const float4* row = (const float4*)(Wq + (size_t)tid*D_);
        #pragma unroll 8
        for (int d=0; d<32; ++d){
          float4 wv = row[d];
          a += wv.x*hs[d*4] + wv.y*hs[d*4+1] + wv.z*hs[d*4+2] + wv.w*hs[d*4+3];
        }
        qs[tid] = a;
      }
      __syncthreads();
      const int len = lens[b];
      for (int s = tid; s < S_; s += 256){
        const float4* kr = (const float4*)(keyv + (size_t)s*P_);
        float a = 0.f;
        #pragma unroll 8
        for (int d=0; d<32; ++d){
          float4 kv = kr[d];
          a += kv.x*qs[d*4] + kv.y*qs[d*4+1] + kv.z*qs[d*4+2] + kv.w*qs[d*4+3];
        }
        es[s] = (s < len) ? a * 0.08838834764831845f : -1e9f;
      }
      __syncthreads();
      float m = -INFINITY;
      for (int s = tid; s < S_; s += 256) m = fmaxf(m, es[s]);
      red3[tid] = m; __syncthreads();
      for (int o = 128; o > 0; o >>= 1){ if (tid < o) red3[tid] = fmaxf(red3[tid], red3[tid+o]); __syncthreads(); }
      m = red3[0]; __syncthreads();
      float psum = 0.f;
      for (int s = tid; s < S_; s += 256){ float p = expf(es[s]-m); es[s] = p; psum += p; }
      red3[tid] = psum; __syncthreads();
      for (int o = 128; o > 0; o >>= 1){ if (tid < o) red3[tid] += red3[tid+o]; __syncthreads(); }
      const float sum = red3[0]; __syncthreads();
      {
        const int p = tid & 127, half = tid >> 7;
        float a = 0.f;
        const float* vp = valv + p;
        #pragma unroll 4
        for (int s = half*200; s < half*200+200; ++s) a += es[s] * vp[(size_t)s*P_];
        red3[tid] = a;
      }
      __syncthreads();
      if (tid < 128){
        float c = (red3[tid] + red3[tid+128]) / sum;
        stA(&ctxg[b*P_ + tid], c);          // cross-block: sc1
        oes[tid] = qs[tid]; oes[128+tid] = c;
      }
      __syncthreads();
      {
        const int v = tid >> 3, k8 = tid & 7;
        float a = 0.f;
        if (v < V_){
          const float* er = embed + (size_t)v*E_ + k8*32;
          const float* oe = oes + k8*32;
          #pragma unroll
          for (int k=0;k<32;++k) a += er[k]*oe[k];
        }
        a += __shfl_down(a, 4, 8);
        a += __shfl_down(a, 2, 8);
        a += __shfl_down(a, 1, 8);
        if (v < V_ && k8 == 0){
          float pv = a + bchar[v];
          preds[v] = pv;
          out[((size_t)b*T_ + t)*V_ + v] = pv;
        }
      }
      __syncthreads();
      if (tid < 32){
        float val = (tid < V_) ? preds[tid] : -INFINITY;
        int idx = tid;
        #pragma unroll
        for (int o = 16; o > 0; o >>= 1){
          float ov = __shfl_down(val, o, 32);
          int oi = __shfl_down(idx, o, 32);
          if (ov > val || (ov == val && oi < idx)){ val = ov; idx = oi; }
        }
        if (tid == 0) stAi(&chrg[b], idx);  // cross-block: sc1
      }
      if (b == 0){
        for (int s = tid; s < S_; s += 256) out[PRED_N + (size_t)t*S_ + s] = es[s]/sum;
      }
    }
    gbar(bar);
  }
}

extern "C" void kernel_launch(void* const* d_in, const int* in_sizes, int n_in,
                              void* d_out, int out_size, void* d_ws, size_t ws_size,
                              hipStream_t stream)
{
  (void)in_sizes; (void)n_in; (void)out_size; (void)ws_size;
  const float* enc   = (const float*)d_in[0];
  const int*   lens  = (const int*)d_in[1];
  const float* embed = (const float*)d_in[2];
  const float* Wih1  = (const float*)d_in[3];
  const float* Whh1  = (const float*)d_in[4];
  const float* bih1  = (const float*)d_in[5];
  const float* bhh1  = (const float*)d_in[6];
  const float* Wih2  = (const float*)d_in[7];
  const float* Whh2  = (const float*)d_in[8];
  const float* bih2  = (const float*)d_in[9];
  const float* bhh2  = (const float*)d_in[10];
  const float* Wk    = (const float*)d_in[11];
  const float* bk    = (const float*)d_in[12];
  const float* Wv    = (const float*)d_in[13];
  const float* bv    = (const float*)d_in[14];
  const float* Wq    = (const float*)d_in[15];
  const float* bq    = (const float*)d_in[16];
  const float* bchar = (const float*)d_in[17];
  float* out = (float*)d_out;
  float* ws  = (float*)d_ws;

  // zero recurrent state + barrier region (poison-proof, replay-deterministic)
  hipMemsetAsync((char*)d_ws + (size_t)H1_OFF*sizeof(float), 0,
                 (size_t)(WS_FLOATS - H1_OFF)*sizeof(float) + 2048, stream);
  hipLaunchKernelGGL(k_kv, dim3(800,4), dim3(256), 0, stream, enc, Wk, bk, Wv, bv, ws);

  // 84 KB dynamic LDS forces 1 block/CU -> all 256 blocks co-resident (grid barrier safe)
  hipFuncSetAttribute((const void*)k_persist,
                      hipFuncAttributeMaxDynamicSharedMemorySize, 86016);
  hipLaunchKernelGGL(k_persist, dim3(NBLK), dim3(256), 86016, stream,
                     embed, Wih1, Whh1, bih1, bhh1,
                     Wih2, Whh2, bih2, bhh2,
                     Wq, bq, bchar, lens, ws, out);
}

// Round 4
// 24940.593 us; speedup vs baseline: 4.6723x; 1.9969x over previous
//
#include <hip/hip_runtime.h>
#include <math.h>

// Problem dims
#define B_   128
#define S_   400
#define ENC_ 512
#define E_   256
#define H_   512
#define D_   128
#define P_   128
#define V_   30
#define T_   600

// Workspace layout (float units)
#define KEYV_OFF 0
#define VALV_OFF (KEYV_OFF + B_*S_*P_)
#define H1_OFF   (VALV_OFF + B_*S_*P_)
#define C1_OFF   (H1_OFF + 2*B_*H_)      // (c1 now in registers; slot kept for layout)
#define H2_OFF   (C1_OFF + B_*H_)
#define C2_OFF   (H2_OFF + 2*B_*D_)
#define CTX_OFF  (C2_OFF + B_*D_)
#define CHR_OFF  (CTX_OFF + B_*P_)
#define WS_FLOATS (CHR_OFF + B_)         // barrier ints live at ws[WS_FLOATS..]

#define PRED_N (B_*T_*V_)
#define NBLK 256
#define NTHR 512

// LDS float offsets
#define W1_BASE 0                        // [16][900]  LSTM1 weight slice (persistent)
#define W2_BASE 14400                    // [16][644]  LSTM2 weight slice (persistent, bid<128)
#define SCR     24704                    // per-phase scratch
#define LDS_FLOATS (SCR + 13056)         // 37760 floats = 151040 B

__device__ __forceinline__ float sigm_(float x){ return 1.0f/(1.0f + expf(-x)); }

// --- agent-scope relaxed atomics (sc1): bypass L1/L2, see coherence point ---
__device__ __forceinline__ float ldA(const float* p){
  return __hip_atomic_load(p, __ATOMIC_RELAXED, __HIP_MEMORY_SCOPE_AGENT);
}
__device__ __forceinline__ void stA(float* p, float v){
  __hip_atomic_store(p, v, __ATOMIC_RELAXED, __HIP_MEMORY_SCOPE_AGENT);
}
__device__ __forceinline__ int ldAi(const int* p){
  return __hip_atomic_load(p, __ATOMIC_RELAXED, __HIP_MEMORY_SCOPE_AGENT);
}
__device__ __forceinline__ void stAi(int* p, int v){
  __hip_atomic_store(p, v, __ATOMIC_RELAXED, __HIP_MEMORY_SCOPE_AGENT);
}
__device__ __forceinline__ void ldA2f(const float* p, float& a, float& b){
  unsigned long long v = __hip_atomic_load((const unsigned long long*)p,
                         __ATOMIC_RELAXED, __HIP_MEMORY_SCOPE_AGENT);
  a = __uint_as_float((unsigned)v);
  b = __uint_as_float((unsigned)(v>>32));
}

// ---- fence-free grid barrier (round-3 proven): tree counters, relaxed sc1 atomics ----
__device__ __forceinline__ void gbar(int* bar){
  __syncthreads();
  if (threadIdx.x == 0){
    const int g0 = __hip_atomic_load(bar, __ATOMIC_RELAXED, __HIP_MEMORY_SCOPE_AGENT);
    asm volatile("" ::: "memory");
    int* leaf = bar + 64 + (blockIdx.x & 7)*32;
    int lo = __hip_atomic_fetch_add(leaf, 1, __ATOMIC_RELAXED, __HIP_MEMORY_SCOPE_AGENT);
    bool done = false;
    if (lo == 31){
      int ro = __hip_atomic_fetch_add(bar+32, 1, __ATOMIC_RELAXED, __HIP_MEMORY_SCOPE_AGENT);
      if (ro == 7){
        #pragma unroll
        for (int i=0;i<8;++i)
          __hip_atomic_store(bar+64+i*32, 0, __ATOMIC_RELAXED, __HIP_MEMORY_SCOPE_AGENT);
        __hip_atomic_store(bar+32, 0, __ATOMIC_RELAXED, __HIP_MEMORY_SCOPE_AGENT);
        asm volatile("s_waitcnt vmcnt(0)" ::: "memory");
        __hip_atomic_fetch_add(bar, 1, __ATOMIC_RELAXED, __HIP_MEMORY_SCOPE_AGENT);
        done = true;
      }
    }
    if (!done){
      while (__hip_atomic_load(bar, __ATOMIC_RELAXED, __HIP_MEMORY_SCOPE_AGENT) == g0)
        __builtin_amdgcn_s_sleep(4);
    }
  }
  __syncthreads();
}

// ---------------- precompute keyv/valv (unchanged, proven) -------------------------------
__global__ __launch_bounds__(256) void k_kv(const float* __restrict__ enc,
    const float* __restrict__ Wk, const float* __restrict__ bk,
    const float* __restrict__ Wv, const float* __restrict__ bv,
    float* __restrict__ ws)
{
  __shared__ float As[32][68];
  __shared__ float Bs[32][68];
  const int tid = threadIdx.x;
  const int tx = tid & 15, ty = tid >> 4;
  const int n0 = blockIdx.x * 64;
  const int c0 = blockIdx.y * 64;
  float acc[4][4] = {};
  for (int k0 = 0; k0 < ENC_; k0 += 32){
    #pragma unroll
    for (int i = 0; i < 8; ++i){
      int idx = tid + 256*i;
      int kk = idx & 31, nl = idx >> 5;
      As[kk][nl] = enc[(size_t)(n0+nl)*ENC_ + k0 + kk];
    }
    #pragma unroll
    for (int i = 0; i < 8; ++i){
      int idx = tid + 256*i;
      int kk = idx & 31, cl = idx >> 5;
      int c = c0 + cl; int p = c & 127;
      const float* W = (c < 128) ? Wk : Wv;
      Bs[kk][cl] = W[(size_t)p*ENC_ + k0 + kk];
    }
    __syncthreads();
    #pragma unroll
    for (int kk = 0; kk < 32; ++kk){
      float4 a4 = *(const float4*)&As[kk][ty*4];
      float4 b4 = *(const float4*)&Bs[kk][tx*4];
      float aa[4] = {a4.x, a4.y, a4.z, a4.w};
      float bb[4] = {b4.x, b4.y, b4.z, b4.w};
      #pragma unroll
      for (int i=0;i<4;++i)
        #pragma unroll
        for (int j=0;j<4;++j) acc[i][j] += aa[i]*bb[j];
    }
    __syncthreads();
  }
  float* keyv = ws + KEYV_OFF;
  float* valv = ws + VALV_OFF;
  #pragma unroll
  for (int i=0;i<4;++i){
    int n = n0 + ty*4 + i; int b = n / S_; int s = n - b*S_;
    #pragma unroll
    for (int j=0;j<4;++j){
      int c = c0 + tx*4 + j;
      float v = acc[i][j];
      if (c < 128) keyv[((size_t)b*S_+s)*P_ + c]       = v + bk[c];
      else         valv[((size_t)b*S_+s)*P_ + (c-128)] = v + bv[c-128];
    }
  }
}

// ---------------- persistent kernel: weights LDS-resident, 512 threads ------------------
__global__ __launch_bounds__(NTHR, 1) void k_persist(
    const float* __restrict__ embed,
    const float* __restrict__ Wih1, const float* __restrict__ Whh1,
    const float* __restrict__ bih1, const float* __restrict__ bhh1,
    const float* __restrict__ Wih2, const float* __restrict__ Whh2,
    const float* __restrict__ bih2, const float* __restrict__ bhh2,
    const float* __restrict__ Wq, const float* __restrict__ bq,
    const float* __restrict__ bchar, const int* __restrict__ lens,
    float* ws, float* out)
{
  extern __shared__ float smem[];
  const int tid = threadIdx.x;
  const int bid = blockIdx.x;
  int* bar = (int*)(ws + WS_FLOATS);

  float* ctxg = ws + CTX_OFF;
  int*   chrg = (int*)(ws + CHR_OFF);

  float* Wl  = smem + W1_BASE;          // [16][900]
  float* W2l = smem + W2_BASE;          // [16][644]
  float* scr = smem + SCR;

  // ---- phase-1 identity ----
  const int ib  = bid & 1;              // item group (64 items)
  const int ug  = bid >> 1;             // unit group (4 units), 0..127
  const int b0  = ib * 64;
  const int sitem = tid >> 3;           // staging: item 0..63
  const int sk8   = (tid & 7) * 8;      // staging: k-offset in panel
  const int gitem = b0 + sitem;
  const int lane  = tid & 63;
  const int w8    = tid >> 6;           // wave 0..7 (K-split within panel)
  const int itq   = lane & 15, rq = lane >> 4;
  const int u1    = tid >> 6;           // pointwise unit-sub (tid<256)
  const int J1    = ug*4 + (u1 & 3);

  // ---- phase-2 identity (bid<128) ----
  const int ig2 = bid & 3;              // item group (32 items)
  const int ug2 = bid >> 2;             // unit group (4 units), 0..31 (valid bid<128)
  const int b02 = ig2 * 32;
  const int sitem2 = tid >> 4;          // staging: item 0..31
  const int sk4    = (tid & 15) * 4;
  const int itemp  = tid & 15;
  const int rowp   = (tid >> 4) & 7;
  const int kw     = tid >> 7;          // 0..3 K-split
  const int u2     = tid >> 5;          // pointwise unit-sub (tid<128)
  const int J2     = ug2*4 + (u2 & 3);

  // ================= one-time: load weight slices into LDS =================
  {
    const int r = tid >> 5, c = tid & 31;          // r = g*4+u
    const int R = (r >> 2)*H_ + ug*4 + (r & 3);    // row of stacked [2048 x ...]
    #pragma unroll
    for (int j = 0; j < 7; ++j){
      int k = c*28 + j*4;
      float4 v;
      if (k < 384) v = *(const float4*)(Wih1 + (size_t)R*384 + k);
      else         v = *(const float4*)(Whh1 + (size_t)R*H_ + (k-384));
      *(float4*)&Wl[r*900 + k] = v;
    }
  }
  if (bid < 128){
    const int r = tid >> 5, c = tid & 31;
    const int R = (r >> 2)*D_ + ug2*4 + (r & 3);   // row of stacked [512 x ...]
    #pragma unroll
    for (int j = 0; j < 5; ++j){
      int k = c*20 + j*4;
      float4 v;
      if (k < 512) v = *(const float4*)(Wih2 + (size_t)R*H_ + k);
      else         v = *(const float4*)(Whh2 + (size_t)R*D_ + (k-512));
      *(float4*)&W2l[r*644 + k] = v;
    }
  }
  __syncthreads();

  // ---- persistent per-thread state & hoisted constants ----
  float c1r = 0.f;                                 // c1[(b0+item), J1] for tid<256
  float c2r = 0.f;                                 // c2[(b02+item), J2] for bid<128, tid<128
  float b1s[4], b2s[4];
  #pragma unroll
  for (int g=0; g<4; ++g){
    b1s[g] = bih1[g*H_ + J1] + bhh1[g*H_ + J1];
    b2s[g] = (bid < 128) ? (bih2[g*D_ + J2] + bhh2[g*D_ + J2]) : 0.f;
  }
  // phase-3 hoists
  const int b3 = bid - 128;
  const float* keyv3 = ws + KEYV_OFF + (size_t)(b3 & 127)*S_*P_;
  const float* valv3 = ws + VALV_OFF + (size_t)(b3 & 127)*S_*P_;
  const int lenb = (bid >= 128) ? lens[b3] : 0;
  const float bqr  = (bid >= 128) ? bq[tid >> 2] : 0.f;
  const float bchr = (bid >= 128 && (tid >> 4) < V_) ? bchar[tid >> 4] : 0.f;

  for (int t = 0; t < T_; ++t){
    // ================= Phase 1: LSTM1 (all 256 blocks) ===================
    {
      const float* h1old = ws + H1_OFF + (size_t)(t&1)*B_*H_;
      float*       h1new = ws + H1_OFF + (size_t)((t+1)&1)*B_*H_;
      float* Xs  = scr;                 // [64][68]
      float* red = scr + 4352;          // [8][16][68]
      const int sch = ldAi(chrg + gitem);

      float acc[4][4] = {};
      float xr[2][8];

      auto LOADX = [&](int p, float* dst){
        int kg = p*64 + sk8;
        if (kg < 256){
          const float* s = embed + (size_t)sch*E_ + kg;
          float4 a = *(const float4*)s, b = *(const float4*)(s+4);
          dst[0]=a.x; dst[1]=a.y; dst[2]=a.z; dst[3]=a.w;
          dst[4]=b.x; dst[5]=b.y; dst[6]=b.z; dst[7]=b.w;
        } else {
          const float* s = (kg < 384) ? (ctxg + (size_t)gitem*P_ + (kg-256))
                                      : (h1old + (size_t)gitem*H_ + (kg-384));
          ldA2f(s+0, dst[0], dst[1]); ldA2f(s+2, dst[2], dst[3]);
          ldA2f(s+4, dst[4], dst[5]); ldA2f(s+6, dst[6], dst[7]);
        }
      };
      LOADX(0, xr[0]); LOADX(1, xr[1]);

      for (int p = 0; p < 14; ++p){
        float* xc = xr[p & 1];
        *(float4*)&Xs[sitem*68 + sk8]     = make_float4(xc[0],xc[1],xc[2],xc[3]);
        *(float4*)&Xs[sitem*68 + sk8 + 4] = make_float4(xc[4],xc[5],xc[6],xc[7]);
        __syncthreads();
        if (p + 2 < 14) LOADX(p + 2, xr[p & 1]);
        #pragma unroll
        for (int it = 0; it < 2; ++it){
          const int kl = w8*8 + it*4;
          const int kg = p*64 + kl;
          float4 xv[4], wv[4];
          #pragma unroll
          for (int i=0;i<4;++i) xv[i] = *(const float4*)&Xs[(itq*4+i)*68 + kl];
          #pragma unroll
          for (int j=0;j<4;++j) wv[j] = *(const float4*)&Wl[(rq*4+j)*900 + kg];
          #pragma unroll
          for (int i=0;i<4;++i){
            #pragma unroll
            for (int j=0;j<4;++j){
              acc[i][j] += xv[i].x*wv[j].x + xv[i].y*wv[j].y
                         + xv[i].z*wv[j].z + xv[i].w*wv[j].w;
            }
          }
        }
        __syncthreads();
      }
      #pragma unroll
      for (int j=0;j<4;++j)
        *(float4*)&red[w8*1088 + (rq*4+j)*68 + itq*4]
          = make_float4(acc[0][j], acc[1][j], acc[2][j], acc[3][j]);
      __syncthreads();
      if (tid < 256){
        const int item = tid & 63;
        float gate[4];
        #pragma unroll
        for (int g=0; g<4; ++g){
          float s = 0.f;
          #pragma unroll
          for (int w=0; w<8; ++w) s += red[w*1088 + (g*4+(u1&3))*68 + item];
          gate[g] = s + b1s[g];
        }
        float cn = sigm_(gate[1])*c1r + sigm_(gate[0])*tanhf(gate[2]);
        float hn = sigm_(gate[3])*tanhf(cn);
        c1r = cn;
        stA(h1new + (size_t)(b0+item)*H_ + J1, hn);
      }
    }
    gbar(bar);

    // ================= Phase 2: LSTM2 (blocks 0..127) ====================
    if (bid < 128){
      const float* h1new = ws + H1_OFF + (size_t)((t+1)&1)*B_*H_;
      const float* h2old = ws + H2_OFF + (size_t)(t&1)*B_*D_;
      float*       h2new = ws + H2_OFF + (size_t)((t+1)&1)*B_*D_;
      float* Xs2  = scr;                // [32][68]
      float* red2 = scr + 2176;         // [4][16][36]

      float acc2[2][2] = {};
      float xr2[2][4];
      auto LOADX2 = [&](int p, float* dst){
        int kg = p*64 + sk4;
        const float* s = (kg < 512) ? (h1new + (size_t)(b02+sitem2)*H_ + kg)
                                    : (h2old + (size_t)(b02+sitem2)*D_ + (kg-512));
        ldA2f(s+0, dst[0], dst[1]); ldA2f(s+2, dst[2], dst[3]);
      };
      LOADX2(0, xr2[0]); LOADX2(1, xr2[1]);

      for (int p = 0; p < 10; ++p){
        float* xc = xr2[p & 1];
        *(float4*)&Xs2[sitem2*68 + sk4] = make_float4(xc[0],xc[1],xc[2],xc[3]);
        __syncthreads();
        if (p + 2 < 10) LOADX2(p + 2, xr2[p & 1]);
        #pragma unroll
        for (int it = 0; it < 4; ++it){
          const int kl = kw*16 + it*4;
          const int kg = p*64 + kl;
          float4 xv[2], wv[2];
          #pragma unroll
          for (int i=0;i<2;++i) xv[i] = *(const float4*)&Xs2[(itemp*2+i)*68 + kl];
          #pragma unroll
          for (int j=0;j<2;++j) wv[j] = *(const float4*)&W2l[(rowp*2+j)*644 + kg];
          #pragma unroll
          for (int i=0;i<2;++i)
            #pragma unroll
            for (int j=0;j<2;++j)
              acc2[i][j] += xv[i].x*wv[j].x + xv[i].y*wv[j].y
                          + xv[i].z*wv[j].z + xv[i].w*wv[j].w;
        }
        __syncthreads();
      }
      #pragma unroll
      for (int i=0;i<2;++i)
        #pragma unroll
        for (int j=0;j<2;++j)
          red2[kw*576 + (rowp*2+j)*36 + itemp*2+i] = acc2[i][j];
      __syncthreads();
      if (tid < 128){
        const int item = tid & 31;
        float gate[4];
        #pragma unroll
        for (int g=0; g<4; ++g){
          float s = 0.f;
          #pragma unroll
          for (int w=0; w<4; ++w) s += red2[w*576 + (g*4+(u2&3))*36 + item];
          gate[g] = s + b2s[g];
        }
        float cn = sigm_(gate[1])*c2r + sigm_(gate[0])*tanhf(gate[2]);
        float hn = sigm_(gate[3])*tanhf(cn);
        c2r = cn;
        stA(h2new + (size_t)(b02+item)*D_ + J2, hn);
      }
    }
    gbar(bar);

    // ================= Phase 3: attention + pred + argmax (blocks 128..255) =
    if (bid >= 128){
      const float* h2new = ws + H2_OFF + (size_t)((t+1)&1)*B_*D_;
      float* hs    = scr;         // 128
      float* qs    = scr + 128;   // 128
      float* es    = scr + 256;   // 408
      float* oes   = scr + 664;   // 256
      float* preds = scr + 920;   // 32
      float* redw  = scr + 952;   // 16
      float* red3  = scr + 968;   // [16][132]

      if (tid < 128) hs[tid] = ldA(h2new + (size_t)b3*D_ + tid);
      __syncthreads();
      {                                  // q = Wq h2 + bq, K-split 4 + shfl
        const int r = tid >> 2, kq = tid & 3;
        const float* wr = Wq + (size_t)r*D_ + kq*32;
        float a = 0.f;
        #pragma unroll
        for (int j=0;j<8;++j){
          float4 wv = *(const float4*)(wr + j*4);
          float4 hv = *(const float4*)&hs[kq*32 + j*4];
          a += wv.x*hv.x + wv.y*hv.y + wv.z*hv.z + wv.w*hv.w;
        }
        a += __shfl_down(a, 2, 4);
        a += __shfl_down(a, 1, 4);
        if (kq == 0) qs[r] = a + bqr;
      }
      __syncthreads();
      float sv = -INFINITY;
      if (tid < S_){                     // scores
        const float4* kr = (const float4*)(keyv3 + (size_t)tid*P_);
        float a = 0.f;
        #pragma unroll 8
        for (int d=0; d<32; ++d){
          float4 kv = kr[d];
          float4 qv = *(const float4*)&qs[d*4];
          a += kv.x*qv.x + kv.y*qv.y + kv.z*qv.z + kv.w*qv.w;
        }
        sv = (tid < lenb) ? a * 0.08838834764831845f : -1e9f;
        es[tid] = sv;
      }
      float mv = sv;                     // max reduce
      #pragma unroll
      for (int o=32; o; o>>=1) mv = fmaxf(mv, __shfl_xor(mv, o));
      if ((tid & 63) == 0) redw[tid >> 6] = mv;
      __syncthreads();
      const float m = fmaxf(fmaxf(fmaxf(redw[0],redw[1]),fmaxf(redw[2],redw[3])),
                            fmaxf(fmaxf(redw[4],redw[5]),fmaxf(redw[6],redw[7])));
      float pv = 0.f;                    // exp + sum
      if (tid < S_){ pv = expf(sv - m); es[tid] = pv; }
      float sm = pv;
      #pragma unroll
      for (int o=32; o; o>>=1) sm += __shfl_xor(sm, o);
      if ((tid & 63) == 0) redw[8 + (tid >> 6)] = sm;
      __syncthreads();
      const float sum = ((redw[8]+redw[9])+(redw[10]+redw[11]))
                      + ((redw[12]+redw[13])+(redw[14]+redw[15]));
      {                                  // PV: 16-way s-split
        const int p4 = tid & 31, sg = tid >> 5;
        float a0=0,a1=0,a2=0,a3=0;
        const float* vb = valv3 + (size_t)(sg*25)*P_ + p4*4;
        #pragma unroll 5
        for (int s2=0; s2<25; ++s2){
          float e = es[sg*25 + s2];
          float4 v = *(const float4*)(vb + (size_t)s2*P_);
          a0 += e*v.x; a1 += e*v.y; a2 += e*v.z; a3 += e*v.w;
        }
        *(float4*)&red3[sg*132 + p4*4] = make_float4(a0,a1,a2,a3);
      }
      __syncthreads();
      if (tid < 128){
        float c = 0.f;
        #pragma unroll
        for (int sg=0; sg<16; ++sg) c += red3[sg*132 + tid];
        c /= sum;
        stA(ctxg + (size_t)b3*P_ + tid, c);
        oes[tid] = qs[tid]; oes[128+tid] = c;
      }
      __syncthreads();
      {                                  // pred + tied-embedding logits
        const int v = tid >> 4, k16 = tid & 15;
        float a = 0.f;
        if (v < V_){
          const float4* er = (const float4*)(embed + (size_t)v*E_ + k16*16);
          #pragma unroll
          for (int j=0;j<4;++j){
            float4 ev = er[j];
            float4 ov = *(const float4*)&oes[k16*16 + j*4];
            a += ev.x*ov.x + ev.y*ov.y + ev.z*ov.z + ev.w*ov.w;
          }
        }
        a += __shfl_down(a, 8, 16);
        a += __shfl_down(a, 4, 16);
        a += __shfl_down(a, 2, 16);
        a += __shfl_down(a, 1, 16);
        if (v < V_ && k16 == 0){
          float pvv = a + bchr;
          preds[v] = pvv;
          out[((size_t)b3*T_ + t)*V_ + v] = pvv;
        }
      }
      __syncthreads();
      if (tid < 32){                     // argmax (numpy first-index tie-break)
        float val = (tid < V_) ? preds[tid] : -INFINITY;
        int idx = tid;
        #pragma unroll
        for (int o = 16; o > 0; o >>= 1){
          float ov = __shfl_down(val, o, 32);
          int oi = __shfl_down(idx, o, 32);
          if (ov > val || (ov == val && oi < idx)){ val = ov; idx = oi; }
        }
        if (tid == 0) stAi(chrg + b3, idx);
      }
      if (b3 == 0 && tid < S_) out[PRED_N + (size_t)t*S_ + tid] = es[tid]/sum;
    }
    gbar(bar);
  }
}

extern "C" void kernel_launch(void* const* d_in, const int* in_sizes, int n_in,
                              void* d_out, int out_size, void* d_ws, size_t ws_size,
                              hipStream_t stream)
{
  (void)in_sizes; (void)n_in; (void)out_size; (void)ws_size;
  const float* enc   = (const float*)d_in[0];
  const int*   lens  = (const int*)d_in[1];
  const float* embed = (const float*)d_in[2];
  const float* Wih1  = (const float*)d_in[3];
  const float* Whh1  = (const float*)d_in[4];
  const float* bih1  = (const float*)d_in[5];
  const float* bhh1  = (const float*)d_in[6];
  const float* Wih2  = (const float*)d_in[7];
  const float* Whh2  = (const float*)d_in[8];
  const float* bih2  = (const float*)d_in[9];
  const float* bhh2  = (const float*)d_in[10];
  const float* Wk    = (const float*)d_in[11];
  const float* bk    = (const float*)d_in[12];
  const float* Wv    = (const float*)d_in[13];
  const float* bv    = (const float*)d_in[14];
  const float* Wq    = (const float*)d_in[15];
  const float* bq    = (const float*)d_in[16];
  const float* bchar = (const float*)d_in[17];
  float* out = (float*)d_out;
  float* ws  = (float*)d_ws;

  // zero recurrent state + barrier region (poison-proof, replay-deterministic)
  hipMemsetAsync((char*)d_ws + (size_t)H1_OFF*sizeof(float), 0,
                 (size_t)(WS_FLOATS - H1_OFF)*sizeof(float) + 2048, stream);
  hipLaunchKernelGGL(k_kv, dim3(800,4), dim3(256), 0, stream, enc, Wk, bk, Wv, bv, ws);

  // 151040 B dynamic LDS -> 1 block/CU, all 256 blocks co-resident (grid barrier safe)
  hipFuncSetAttribute((const void*)k_persist,
                      hipFuncAttributeMaxDynamicSharedMemorySize, LDS_FLOATS*4);
  hipLaunchKernelGGL(k_persist, dim3(NBLK), dim3(NTHR), LDS_FLOATS*4, stream,
                     embed, Wih1, Whh1, bih1, bhh1,
                     Wih2, Whh2, bih2, bhh2,
                     Wq, bq, bchar, lens, ws, out);
}